// Round 4
// baseline (36.892 us; speedup 1.0000x reference)
//
#include <hip/hip_runtime.h>

// ---------------------------------------------------------------------------
// Compile-time wavelet-packet response matrix A[64][50]:
// A[j*8+m][n] = coefficient of x[n] in leaf j, sample m (3-level sym2, zero pad).
// Geometry: 50 -> 26 -> 14 -> 8, pad ph=2 both sides at every level (all even).
// ---------------------------------------------------------------------------
struct Amat { float a[64][50]; };

constexpr Amat makeA() {
    constexpr float h0[4] = { 0.48296291314453416f,  0.8365163037378079f,
                              0.22414386804185735f, -0.12940952255126037f};
    constexpr float h1[4] = {-0.12940952255126037f, -0.22414386804185735f,
                              0.8365163037378079f,  -0.48296291314453416f};
    float L1[2][26][50] = {};
    for (int band = 0; band < 2; ++band)
        for (int m = 0; m < 26; ++m)
            for (int n = 0; n < 50; ++n) {
                int k = n - 2 * m + 2;
                L1[band][m][n] = (k >= 0 && k < 4) ? (band ? h1[k] : h0[k]) : 0.0f;
            }
    float L2[4][14][50] = {};
    for (int j = 0; j < 4; ++j)
        for (int m = 0; m < 14; ++m)
            for (int n = 0; n < 50; ++n) {
                float acc = 0.0f;
                for (int k = 0; k < 4; ++k) {
                    int p = 2 * m + k - 2;
                    if (p >= 0 && p < 26)
                        acc += (j & 1 ? h1[k] : h0[k]) * L1[j >> 1][p][n];
                }
                L2[j][m][n] = acc;
            }
    Amat A = {};
    for (int j = 0; j < 8; ++j)
        for (int m = 0; m < 8; ++m)
            for (int n = 0; n < 50; ++n) {
                float acc = 0.0f;
                for (int k = 0; k < 4; ++k) {
                    int p = 2 * m + k - 2;
                    if (p >= 0 && p < 14)
                        acc += (j & 1 ? h1[k] : h0[k]) * L2[j >> 1][p][n];
                }
                A.a[j * 8 + m][n] = acc;
            }
    return A;
}

__device__ __constant__ Amat cA = makeA();

// ---------------------------------------------------------------------------
// Kernel 1: fold W (5x192) with A into M, FLAT layout Mg[i*5+k], i = c*50+n.
// ---------------------------------------------------------------------------
__global__ __launch_bounds__(256) void build_M(const float* __restrict__ W,
                                               float* __restrict__ Mg) {
    const int i = threadIdx.x;
    if (i >= 150) return;
    const int c = i / 50, n = i - c * 50;
    float acc0 = 0.f, acc1 = 0.f, acc2 = 0.f, acc3 = 0.f, acc4 = 0.f;
    for (int f = 0; f < 64; ++f) {          // f = j*8 + s
        const float av = cA.a[f][n];
        const int wj = (f >> 3) * 24 + c * 8 + (f & 7);
        acc0 = fmaf(W[0 * 192 + wj], av, acc0);
        acc1 = fmaf(W[1 * 192 + wj], av, acc1);
        acc2 = fmaf(W[2 * 192 + wj], av, acc2);
        acc3 = fmaf(W[3 * 192 + wj], av, acc3);
        acc4 = fmaf(W[4 * 192 + wj], av, acc4);
    }
    float* dst = &Mg[i * 5];
    dst[0] = acc0; dst[1] = acc1; dst[2] = acc2; dst[3] = acc3; dst[4] = acc4;
}

// ---------------------------------------------------------------------------
// Kernel 2: 1 wave per block, 1 row per lane, NCH chunks of 64 rows.
// x staged global->LDS via global_load_lds (linear, coalesced), double-buffered
// with counted vmcnt so next chunk's loads fly under current chunk's compute.
// M via wave-uniform indices -> scalar-cache s_load (no LDS, no VMEM per lane).
// ---------------------------------------------------------------------------
#define NCH   4
#define CROWS 64
#define CHW   (CROWS * 150)          // 9600 words per chunk
#define CHB   (CHW * 4)              // 38400 bytes per chunk

typedef const __attribute__((address_space(1))) void* gptr_t;
typedef       __attribute__((address_space(3))) void* lptr_t;

__global__ __launch_bounds__(64) void dwt_gemv(const float* __restrict__ x,
                                               const float* __restrict__ Mg,
                                               const float* __restrict__ bias,
                                               float* __restrict__ out) {
    extern __shared__ float sX[];    // 2 * CHW floats (76.8 KB)
    const int lane = threadIdx.x;
    const size_t row0 = (size_t)blockIdx.x * (NCH * CROWS);

    const float b0 = bias[0], b1 = bias[1], b2 = bias[2], b3 = bias[3], b4 = bias[4];

    // stage chunk `ch` into buffer `buf` (39 vmem ops: 37 x 1KB + 2 x 256B)
    auto issue = [&](int buf, int ch) {
        const char* g = (const char*)(x + (row0 + (size_t)ch * CROWS) * 150);
        char* l = (char*)sX + buf * CHB;
        #pragma unroll
        for (int j = 0; j < 37; ++j)
            __builtin_amdgcn_global_load_lds((gptr_t)(g + j * 1024 + lane * 16),
                                             (lptr_t)(l + j * 1024), 16, 0, 0);
        #pragma unroll
        for (int j = 0; j < 2; ++j)
            __builtin_amdgcn_global_load_lds((gptr_t)(g + 37888 + j * 256 + lane * 4),
                                             (lptr_t)(l + 37888 + j * 256), 4, 0, 0);
    };

    issue(0, 0);

    for (int c = 0; c < NCH; ++c) {
        if (c + 1 < NCH) {
            issue((c + 1) & 1, c + 1);
            // wait for chunk c's loads (and older stores); keep c+1's 39 in flight
            asm volatile("s_waitcnt vmcnt(39)" ::: "memory");
        } else {
            asm volatile("s_waitcnt vmcnt(0)" ::: "memory");
        }

        const float2* xr = (const float2*)(sX + (c & 1) * CHW + lane * 150);
        float a0 = 0.f, a1 = 0.f, a2 = 0.f, a3 = 0.f, a4 = 0.f;
        #pragma unroll 15
        for (int g = 0; g < 75; ++g) {
            const float2 xv = xr[g];
            const float* m = Mg + g * 10;      // wave-uniform -> s_load
            a0 = fmaf(m[0], xv.x, a0);
            a1 = fmaf(m[1], xv.x, a1);
            a2 = fmaf(m[2], xv.x, a2);
            a3 = fmaf(m[3], xv.x, a3);
            a4 = fmaf(m[4], xv.x, a4);
            a0 = fmaf(m[5], xv.y, a0);
            a1 = fmaf(m[6], xv.y, a1);
            a2 = fmaf(m[7], xv.y, a2);
            a3 = fmaf(m[8], xv.y, a3);
            a4 = fmaf(m[9], xv.y, a4);
        }

        float* o = out + (row0 + (size_t)c * CROWS + lane) * 5;
        o[0] = a0 + b0;
        o[1] = a1 + b1;
        o[2] = a2 + b2;
        o[3] = a3 + b3;
        o[4] = a4 + b4;
    }
}

extern "C" void kernel_launch(void* const* d_in, const int* in_sizes, int n_in,
                              void* d_out, int out_size, void* d_ws, size_t ws_size,
                              hipStream_t stream) {
    const float* x    = (const float*)d_in[0];   // (131072, 3, 50)
    const float* W    = (const float*)d_in[1];   // (5, 192)
    const float* bias = (const float*)d_in[2];   // (5,)
    float*       out  = (float*)d_out;           // (131072, 5)
    float*       Mg   = (float*)d_ws;            // 750 floats, flat [i][k]

    build_M<<<1, 256, 0, stream>>>(W, Mg);

    const int B = in_sizes[0] / 150;             // 131072
    const int grid = B / (NCH * CROWS);          // 512 blocks (2 per CU)
    const size_t smem = 2 * CHB;                 // 76.8 KB dynamic LDS

    // allow >64KB dynamic LDS (non-stream call; capture-safe, deterministic)
    (void)hipFuncSetAttribute((const void*)dwt_gemv,
                              hipFuncAttributeMaxDynamicSharedMemorySize,
                              (int)smem);

    dwt_gemv<<<grid, 64, smem, stream>>>(x, Mg, bias, out);
}

// Round 6
// 36.018 us; speedup vs baseline: 1.0242x; 1.0242x over previous
//
#include <hip/hip_runtime.h>

// ---------------------------------------------------------------------------
// Compile-time wavelet-packet response matrix A[64][50]:
// A[j*8+m][n] = coefficient of x[n] in leaf j, sample m (3-level sym2, zero pad).
// Geometry: 50 -> 26 -> 14 -> 8, pad ph=2 both sides at every level (all even).
// ---------------------------------------------------------------------------
struct Amat { float a[64][50]; };

constexpr Amat makeA() {
    constexpr float h0[4] = { 0.48296291314453416f,  0.8365163037378079f,
                              0.22414386804185735f, -0.12940952255126037f};
    constexpr float h1[4] = {-0.12940952255126037f, -0.22414386804185735f,
                              0.8365163037378079f,  -0.48296291314453416f};
    float L1[2][26][50] = {};
    for (int band = 0; band < 2; ++band)
        for (int m = 0; m < 26; ++m)
            for (int n = 0; n < 50; ++n) {
                int k = n - 2 * m + 2;
                L1[band][m][n] = (k >= 0 && k < 4) ? (band ? h1[k] : h0[k]) : 0.0f;
            }
    float L2[4][14][50] = {};
    for (int j = 0; j < 4; ++j)
        for (int m = 0; m < 14; ++m)
            for (int n = 0; n < 50; ++n) {
                float acc = 0.0f;
                for (int k = 0; k < 4; ++k) {
                    int p = 2 * m + k - 2;
                    if (p >= 0 && p < 26)
                        acc += (j & 1 ? h1[k] : h0[k]) * L1[j >> 1][p][n];
                }
                L2[j][m][n] = acc;
            }
    Amat A = {};
    for (int j = 0; j < 8; ++j)
        for (int m = 0; m < 8; ++m)
            for (int n = 0; n < 50; ++n) {
                float acc = 0.0f;
                for (int k = 0; k < 4; ++k) {
                    int p = 2 * m + k - 2;
                    if (p >= 0 && p < 14)
                        acc += (j & 1 ? h1[k] : h0[k]) * L2[j >> 1][p][n];
                }
                A.a[j * 8 + m][n] = acc;
            }
    return A;
}

__device__ __constant__ Amat cA = makeA();

// ---------------------------------------------------------------------------
// Kernel 1: fold W (5x192) with A into M, FLAT layout Mg[i*5+k], i = c*50+n.
// ---------------------------------------------------------------------------
__global__ __launch_bounds__(256) void build_M(const float* __restrict__ W,
                                               float* __restrict__ Mg) {
    const int i = threadIdx.x;
    if (i >= 150) return;
    const int c = i / 50, n = i - c * 50;
    float acc0 = 0.f, acc1 = 0.f, acc2 = 0.f, acc3 = 0.f, acc4 = 0.f;
    for (int f = 0; f < 64; ++f) {          // f = j*8 + s
        const float av = cA.a[f][n];
        const int wj = (f >> 3) * 24 + c * 8 + (f & 7);
        acc0 = fmaf(W[0 * 192 + wj], av, acc0);
        acc1 = fmaf(W[1 * 192 + wj], av, acc1);
        acc2 = fmaf(W[2 * 192 + wj], av, acc2);
        acc3 = fmaf(W[3 * 192 + wj], av, acc3);
        acc4 = fmaf(W[4 * 192 + wj], av, acc4);
    }
    float* dst = &Mg[i * 5];
    dst[0] = acc0; dst[1] = acc1; dst[2] = acc2; dst[3] = acc3; dst[4] = acc4;
}

// ---------------------------------------------------------------------------
// Kernel 2: 256 threads/block, one row per thread, 256 rows/block.
// 5 feature-phases of 30 floats/row; staged global->LDS via global_load_lds
// width 4, flat lane-consecutive sweep. NOTE (rule #21 / m104): the LDS dest
// of global_load_lds is PER-WAVE (uniform base + inwave_lane*4) -> each wave
// must get its own base: l + s*256 + (tid & 192). Double-buffered, counted
// vmcnt(30), raw s_barrier. M via wave-uniform s_load; accumulators persist.
// ---------------------------------------------------------------------------
#define RPB 256
#define PHW 30                    // floats per row per phase
#define CHW (RPB * PHW)           // 7680 dwords per phase buffer (30720 B)

typedef const __attribute__((address_space(1))) void* gptr_t;
typedef       __attribute__((address_space(3))) void* lptr_t;

__global__ __launch_bounds__(256) void dwt_gemv(const float* __restrict__ x,
                                                const float* __restrict__ Mg,
                                                const float* __restrict__ bias,
                                                float* __restrict__ out) {
    __shared__ float sX[2 * CHW];           // 61440 B -> 2 blocks/CU
    const int tid = threadIdx.x;
    const int wbase = tid & 192;            // wave-uniform: 64 * (wave index)
    const size_t row0 = (size_t)blockIdx.x * RPB;
    const float* __restrict__ xb = x + row0 * 150;

    // stage phase ch into buffer buf: 30 flat dword sweeps.
    // flat f = s*256 + tid ; source dword = (f/30)*150 + ch*30 + (f%30)
    // dest: per-wave base (l + s*256 + wbase); HW adds inwave_lane*4.
    auto issue = [&](int buf, int ch) {
        float* l = sX + buf * CHW;
        #pragma unroll
        for (int s = 0; s < 30; ++s) {
            const int f = s * 256 + tid;
            const int r = f / 30, j = f - r * 30;
            __builtin_amdgcn_global_load_lds((gptr_t)(xb + r * 150 + ch * 30 + j),
                                             (lptr_t)(l + s * 256 + wbase), 4, 0, 0);
        }
    };

    issue(0, 0);

    float a0 = 0.f, a1 = 0.f, a2 = 0.f, a3 = 0.f, a4 = 0.f;

    #pragma unroll
    for (int ch = 0; ch < 5; ++ch) {
        if (ch + 1 < 5) {
            issue((ch + 1) & 1, ch + 1);
            asm volatile("s_waitcnt vmcnt(30)" ::: "memory");  // cur landed, next in flight
        } else {
            asm volatile("s_waitcnt vmcnt(0)" ::: "memory");
        }
        __builtin_amdgcn_s_barrier();
        __builtin_amdgcn_sched_barrier(0);

        const float2* __restrict__ xr =
            (const float2*)(sX + (ch & 1) * CHW + tid * PHW);
        #pragma unroll
        for (int j = 0; j < 15; ++j) {
            const float2 xv = xr[j];
            const float* m = Mg + (ch * 30 + 2 * j) * 5;   // wave-uniform -> s_load
            a0 = fmaf(m[0], xv.x, a0);
            a1 = fmaf(m[1], xv.x, a1);
            a2 = fmaf(m[2], xv.x, a2);
            a3 = fmaf(m[3], xv.x, a3);
            a4 = fmaf(m[4], xv.x, a4);
            a0 = fmaf(m[5], xv.y, a0);
            a1 = fmaf(m[6], xv.y, a1);
            a2 = fmaf(m[7], xv.y, a2);
            a3 = fmaf(m[8], xv.y, a3);
            a4 = fmaf(m[9], xv.y, a4);
        }
        __builtin_amdgcn_sched_barrier(0);
        __builtin_amdgcn_s_barrier();       // all waves done reading this buffer
    }

    float* o = out + (row0 + tid) * 5;
    o[0] = a0 + bias[0];
    o[1] = a1 + bias[1];
    o[2] = a2 + bias[2];
    o[3] = a3 + bias[3];
    o[4] = a4 + bias[4];
}

extern "C" void kernel_launch(void* const* d_in, const int* in_sizes, int n_in,
                              void* d_out, int out_size, void* d_ws, size_t ws_size,
                              hipStream_t stream) {
    const float* x    = (const float*)d_in[0];   // (131072, 3, 50)
    const float* W    = (const float*)d_in[1];   // (5, 192)
    const float* bias = (const float*)d_in[2];   // (5,)
    float*       out  = (float*)d_out;           // (131072, 5)
    float*       Mg   = (float*)d_ws;            // 750 floats, flat [i][k]

    build_M<<<1, 256, 0, stream>>>(W, Mg);

    const int B = in_sizes[0] / 150;             // 131072
    dwt_gemv<<<B / RPB, 256, 0, stream>>>(x, Mg, bias, out);
}

// Round 7
// 28.976 us; speedup vs baseline: 1.2732x; 1.2430x over previous
//
#include <hip/hip_runtime.h>

// ---------------------------------------------------------------------------
// Compile-time wavelet-packet response matrix A[64][50]:
// A[j*8+m][n] = coefficient of x[n] in leaf j, sample m (3-level sym2, zero pad).
// Geometry: 50 -> 26 -> 14 -> 8, pad ph=2 both sides at every level (all even).
// ---------------------------------------------------------------------------
struct Amat { float a[64][50]; };

constexpr Amat makeA() {
    constexpr float h0[4] = { 0.48296291314453416f,  0.8365163037378079f,
                              0.22414386804185735f, -0.12940952255126037f};
    constexpr float h1[4] = {-0.12940952255126037f, -0.22414386804185735f,
                              0.8365163037378079f,  -0.48296291314453416f};
    float L1[2][26][50] = {};
    for (int band = 0; band < 2; ++band)
        for (int m = 0; m < 26; ++m)
            for (int n = 0; n < 50; ++n) {
                int k = n - 2 * m + 2;
                L1[band][m][n] = (k >= 0 && k < 4) ? (band ? h1[k] : h0[k]) : 0.0f;
            }
    float L2[4][14][50] = {};
    for (int j = 0; j < 4; ++j)
        for (int m = 0; m < 14; ++m)
            for (int n = 0; n < 50; ++n) {
                float acc = 0.0f;
                for (int k = 0; k < 4; ++k) {
                    int p = 2 * m + k - 2;
                    if (p >= 0 && p < 26)
                        acc += (j & 1 ? h1[k] : h0[k]) * L1[j >> 1][p][n];
                }
                L2[j][m][n] = acc;
            }
    Amat A = {};
    for (int j = 0; j < 8; ++j)
        for (int m = 0; m < 8; ++m)
            for (int n = 0; n < 50; ++n) {
                float acc = 0.0f;
                for (int k = 0; k < 4; ++k) {
                    int p = 2 * m + k - 2;
                    if (p >= 0 && p < 14)
                        acc += (j & 1 ? h1[k] : h0[k]) * L2[j >> 1][p][n];
                }
                A.a[j * 8 + m][n] = acc;
            }
    return A;
}

__device__ __constant__ Amat cA = makeA();

// ---------------------------------------------------------------------------
// Kernel 1 (v2): fold W (5x192) with A into Mg, PAIR-GROUPED layout
//   Mg[g*12 + p*5 + k],  i = 2g+p.
// W staged to LDS (coalesced); f-loop unrolled x16 so the 64 cA vector loads
// pipeline in 4 latency walls instead of 64 serialized ones.
// ---------------------------------------------------------------------------
__global__ __launch_bounds__(256) void build_M(const float* __restrict__ W,
                                               float* __restrict__ Mg) {
    __shared__ float sW[960];
    const int tid = threadIdx.x;
    #pragma unroll
    for (int t = 0; t < 4; ++t) {
        const int idx = tid + t * 256;
        if (idx < 960) sW[idx] = W[idx];
    }
    __syncthreads();

    const int i = tid;
    if (i >= 150) return;
    const int c = i / 50, n = i - c * 50;
    float acc0 = 0.f, acc1 = 0.f, acc2 = 0.f, acc3 = 0.f, acc4 = 0.f;
    #pragma unroll 16
    for (int f = 0; f < 64; ++f) {          // f = j*8 + s
        const float av = cA.a[f][n];        // lanes read consecutive dwords
        const int wj = (f >> 3) * 24 + c * 8 + (f & 7);   // LDS, 2-way broadcast
        acc0 = fmaf(sW[0 * 192 + wj], av, acc0);
        acc1 = fmaf(sW[1 * 192 + wj], av, acc1);
        acc2 = fmaf(sW[2 * 192 + wj], av, acc2);
        acc3 = fmaf(sW[3 * 192 + wj], av, acc3);
        acc4 = fmaf(sW[4 * 192 + wj], av, acc4);
    }
    const int g = i >> 1, p = i & 1;
    float* dst = &Mg[g * 12 + p * 5];
    dst[0] = acc0; dst[1] = acc1; dst[2] = acc2; dst[3] = acc3; dst[4] = acc4;
}

// ---------------------------------------------------------------------------
// Kernel 2: byte-identical to the measured-best (R3, 31.8us) gemv.
// One thread per batch row; M from LDS via wave-uniform broadcast b128/b64;
// x straight global->register, 75 float2 per thread.
// ---------------------------------------------------------------------------
__global__ __launch_bounds__(256) void dwt_gemv(const float* __restrict__ x,
                                                const float* __restrict__ Mg,
                                                const float* __restrict__ bias,
                                                float* __restrict__ out) {
    __shared__ float sM[75 * 12];
    const int tid = threadIdx.x;
    for (int idx = tid; idx < 900; idx += 256) sM[idx] = Mg[idx];
    __syncthreads();

    const size_t r = (size_t)blockIdx.x * 256 + tid;
    const float2* __restrict__ xr = (const float2*)(x + r * 150);  // 8B aligned

    float a0 = 0.f, a1 = 0.f, a2 = 0.f, a3 = 0.f, a4 = 0.f;
    #pragma unroll 25
    for (int g = 0; g < 75; ++g) {
        const float2 xv = xr[g];
        const float4 m0 = *(const float4*)&sM[g * 12 + 0];   // rows 2g (k0..3)
        const float4 m1 = *(const float4*)&sM[g * 12 + 4];   // 2g k4, 2g+1 k0..2
        const float2 m2 = *(const float2*)&sM[g * 12 + 8];   // 2g+1 k3..4
        a0 = fmaf(m0.x, xv.x, a0);
        a1 = fmaf(m0.y, xv.x, a1);
        a2 = fmaf(m0.z, xv.x, a2);
        a3 = fmaf(m0.w, xv.x, a3);
        a4 = fmaf(m1.x, xv.x, a4);
        a0 = fmaf(m1.y, xv.y, a0);
        a1 = fmaf(m1.z, xv.y, a1);
        a2 = fmaf(m1.w, xv.y, a2);
        a3 = fmaf(m2.x, xv.y, a3);
        a4 = fmaf(m2.y, xv.y, a4);
    }

    float* o = &out[r * 5];
    o[0] = a0 + bias[0];
    o[1] = a1 + bias[1];
    o[2] = a2 + bias[2];
    o[3] = a3 + bias[3];
    o[4] = a4 + bias[4];
}

extern "C" void kernel_launch(void* const* d_in, const int* in_sizes, int n_in,
                              void* d_out, int out_size, void* d_ws, size_t ws_size,
                              hipStream_t stream) {
    const float* x    = (const float*)d_in[0];   // (131072, 3, 50)
    const float* W    = (const float*)d_in[1];   // (5, 192)
    const float* bias = (const float*)d_in[2];   // (5,)
    float*       out  = (float*)d_out;           // (131072, 5)
    float*       Mg   = (float*)d_ws;            // 900 floats, pair-grouped

    build_M<<<1, 256, 0, stream>>>(W, Mg);

    const int B = in_sizes[0] / 150;             // 131072
    dwt_gemv<<<B / 256, 256, 0, stream>>>(x, Mg, bias, out);
}

// Round 8
// 27.604 us; speedup vs baseline: 1.3365x; 1.0497x over previous
//
#include <hip/hip_runtime.h>

// ---------------------------------------------------------------------------
// Compile-time wavelet-packet response matrix A[64][50]:
// A[j*8+m][n] = coefficient of x[n] in leaf j, sample m (3-level sym2, zero pad).
// Geometry: 50 -> 26 -> 14 -> 8, pad ph=2 both sides at every level (all even).
// ---------------------------------------------------------------------------
struct Amat { float a[64][50]; };

constexpr Amat makeA() {
    constexpr float h0[4] = { 0.48296291314453416f,  0.8365163037378079f,
                              0.22414386804185735f, -0.12940952255126037f};
    constexpr float h1[4] = {-0.12940952255126037f, -0.22414386804185735f,
                              0.8365163037378079f,  -0.48296291314453416f};
    float L1[2][26][50] = {};
    for (int band = 0; band < 2; ++band)
        for (int m = 0; m < 26; ++m)
            for (int n = 0; n < 50; ++n) {
                int k = n - 2 * m + 2;
                L1[band][m][n] = (k >= 0 && k < 4) ? (band ? h1[k] : h0[k]) : 0.0f;
            }
    float L2[4][14][50] = {};
    for (int j = 0; j < 4; ++j)
        for (int m = 0; m < 14; ++m)
            for (int n = 0; n < 50; ++n) {
                float acc = 0.0f;
                for (int k = 0; k < 4; ++k) {
                    int p = 2 * m + k - 2;
                    if (p >= 0 && p < 26)
                        acc += (j & 1 ? h1[k] : h0[k]) * L1[j >> 1][p][n];
                }
                L2[j][m][n] = acc;
            }
    Amat A = {};
    for (int j = 0; j < 8; ++j)
        for (int m = 0; m < 8; ++m)
            for (int n = 0; n < 50; ++n) {
                float acc = 0.0f;
                for (int k = 0; k < 4; ++k) {
                    int p = 2 * m + k - 2;
                    if (p >= 0 && p < 14)
                        acc += (j & 1 ? h1[k] : h0[k]) * L2[j >> 1][p][n];
                }
                A.a[j * 8 + m][n] = acc;
            }
    return A;
}

__device__ __constant__ Amat cA = makeA();

// 5 fmas of element xv (feature ib) into the row accumulators
#define FMA_EL(A0,A1,A2,A3,A4, xv, ib)            \
    A0 = fmaf(sM[(ib) * 5 + 0], (xv), A0);        \
    A1 = fmaf(sM[(ib) * 5 + 1], (xv), A1);        \
    A2 = fmaf(sM[(ib) * 5 + 2], (xv), A2);        \
    A3 = fmaf(sM[(ib) * 5 + 3], (xv), A3);        \
    A4 = fmaf(sM[(ib) * 5 + 4], (xv), A4);

// ---------------------------------------------------------------------------
// Fused kernel: 256 blocks (1 per CU), 256 threads, 512 rows/block (2/thread).
// Prologue: block-local fold of W with cA into sM[i*5+k] (i = c*50+n).
// Main: thread owns rows 2t,2t+1 -> one contiguous 1200B stream of 75 aligned
// float4 loads (halves TA line-lookups vs float2-per-row). M via wave-uniform
// LDS broadcast (16B-aligned 20-float runs -> b128s). 8 loads hoisted above
// the prologue to cover its latency.
// ---------------------------------------------------------------------------
__global__ __launch_bounds__(256) void dwt_fused(const float* __restrict__ x,
                                                 const float* __restrict__ W,
                                                 const float* __restrict__ bias,
                                                 float* __restrict__ out) {
    __shared__ float sW[960];
    __shared__ float sM[752];        // flat [i*5+k], 750 used
    const int tid = threadIdx.x;
    const size_t r0 = (size_t)blockIdx.x * 512 + 2 * (size_t)tid;
    const float4* __restrict__ xr = (const float4*)(x + r0 * 150); // 1200B, 16B-aligned

    // hoist first 8 x-loads so they fly under the M prologue
    float4 q0 = xr[0], q1 = xr[1], q2 = xr[2], q3 = xr[3];
    float4 q4 = xr[4], q5 = xr[5], q6 = xr[6], q7 = xr[7];

    #pragma unroll
    for (int t = 0; t < 4; ++t) {
        const int idx = tid + t * 256;
        if (idx < 960) sW[idx] = W[idx];
    }
    __syncthreads();

    if (tid < 150) {
        const int c = tid / 50, n = tid - c * 50;
        float m0 = 0.f, m1 = 0.f, m2 = 0.f, m3 = 0.f, m4 = 0.f;
        #pragma unroll 16
        for (int f = 0; f < 64; ++f) {              // f = j*8 + s
            const float av = cA.a[f][n];
            const int wj = (f >> 3) * 24 + c * 8 + (f & 7);
            m0 = fmaf(sW[0 * 192 + wj], av, m0);
            m1 = fmaf(sW[1 * 192 + wj], av, m1);
            m2 = fmaf(sW[2 * 192 + wj], av, m2);
            m3 = fmaf(sW[3 * 192 + wj], av, m3);
            m4 = fmaf(sW[4 * 192 + wj], av, m4);
        }
        float* dst = &sM[tid * 5];
        dst[0] = m0; dst[1] = m1; dst[2] = m2; dst[3] = m3; dst[4] = m4;
    }
    __syncthreads();

    float a0 = 0.f, a1 = 0.f, a2 = 0.f, a3 = 0.f, a4 = 0.f;   // row 2t
    float b0 = 0.f, b1 = 0.f, b2 = 0.f, b3 = 0.f, b4 = 0.f;   // row 2t+1

    // j = 0..7 from hoisted registers (row0, features 4j..4j+3)
    {
        const float4 qs[8] = {q0, q1, q2, q3, q4, q5, q6, q7};
        #pragma unroll
        for (int j = 0; j < 8; ++j) {
            const float4 q = qs[j];
            FMA_EL(a0,a1,a2,a3,a4, q.x, 4*j + 0)
            FMA_EL(a0,a1,a2,a3,a4, q.y, 4*j + 1)
            FMA_EL(a0,a1,a2,a3,a4, q.z, 4*j + 2)
            FMA_EL(a0,a1,a2,a3,a4, q.w, 4*j + 3)
        }
    }
    // j = 8..36: row0
    #pragma unroll 8
    for (int j = 8; j < 37; ++j) {
        const float4 q = xr[j];
        FMA_EL(a0,a1,a2,a3,a4, q.x, 4*j + 0)
        FMA_EL(a0,a1,a2,a3,a4, q.y, 4*j + 1)
        FMA_EL(a0,a1,a2,a3,a4, q.z, 4*j + 2)
        FMA_EL(a0,a1,a2,a3,a4, q.w, 4*j + 3)
    }
    // j = 37: straddles rows (features 148,149 of row0; 0,1 of row1)
    {
        const float4 q = xr[37];
        FMA_EL(a0,a1,a2,a3,a4, q.x, 148)
        FMA_EL(a0,a1,a2,a3,a4, q.y, 149)
        FMA_EL(b0,b1,b2,b3,b4, q.z, 0)
        FMA_EL(b0,b1,b2,b3,b4, q.w, 1)
    }
    // j = 38..74: row1, features 4j-150 .. 4j-147
    #pragma unroll 8
    for (int j = 38; j < 75; ++j) {
        const float4 q = xr[j];
        const int ib = 4*j - 150;
        FMA_EL(b0,b1,b2,b3,b4, q.x, ib + 0)
        FMA_EL(b0,b1,b2,b3,b4, q.y, ib + 1)
        FMA_EL(b0,b1,b2,b3,b4, q.z, ib + 2)
        FMA_EL(b0,b1,b2,b3,b4, q.w, ib + 3)
    }

    const float c0 = bias[0], c1 = bias[1], c2 = bias[2], c3 = bias[3], c4 = bias[4];
    float* o = out + r0 * 5;
    o[0] = a0 + c0;  o[1] = a1 + c1;  o[2] = a2 + c2;  o[3] = a3 + c3;  o[4] = a4 + c4;
    o[5] = b0 + c0;  o[6] = b1 + c1;  o[7] = b2 + c2;  o[8] = b3 + c3;  o[9] = b4 + c4;
}

extern "C" void kernel_launch(void* const* d_in, const int* in_sizes, int n_in,
                              void* d_out, int out_size, void* d_ws, size_t ws_size,
                              hipStream_t stream) {
    const float* x    = (const float*)d_in[0];   // (131072, 3, 50)
    const float* W    = (const float*)d_in[1];   // (5, 192)
    const float* bias = (const float*)d_in[2];   // (5,)
    float*       out  = (float*)d_out;           // (131072, 5)

    const int B = in_sizes[0] / 150;             // 131072
    dwt_fused<<<B / 512, 256, 0, stream>>>(x, W, bias, out);
}